// Round 14
// baseline (276.829 us; speedup 1.0000x reference)
//
#include <hip/hip_runtime.h>
#include <cmath>

#define CH 32
#define NBASIS 8
#define NPATH 11
#define NF 13            // features per channel: 1 + 3 + 9
#define NPF (NF * CH)    // 416 f32 per node
#define MAXDEG 40        // slot capacity; Poisson(10) -> P(overflow) ~ 1e-8
#define NW 4             // nodes (waves) per 256-thread block (edge kernel)

typedef unsigned int u32;
typedef __fp16 half2_t __attribute__((ext_vector_type(2)));

// ---- LDS: edge phase only (epilogue is wave-local, register-based) ---------
#define SM_SREC_OFF 5632
#define SMEM_TOTAL  10752     // sW4 5632 + srec 5120 (R10 footprint)

__device__ __forceinline__ float silu_f(float x) {
    return x / (1.0f + __expf(-x));
}

__device__ __forceinline__ u32 bf16r(float x) {   // round-to-nearest bf16 bits
    return (__float_as_uint(x) + 0x8000u) >> 16;
}
__device__ __forceinline__ float bf16lo(u32 w) {  // low 16 bits -> f32
    return __uint_as_float(w << 16);
}
__device__ __forceinline__ float bf16hi(u32 w) {  // high 16 bits -> f32
    return __uint_as_float(w & 0xffff0000u);
}

// pack two f32 -> f16x2 dword (v_cvt_pkrtz_f16_f32)
__device__ __forceinline__ u32 f16pk(float a, float b) {
    union { half2_t h; u32 u; } cv;
    cv.h = __builtin_amdgcn_cvt_pkrtz(a, b);
    return cv.u;
}
__device__ __forceinline__ half2_t ash2(u32 w) {
    union { u32 u; half2_t h; } cv; cv.u = w; return cv.h;
}

// f32 += f16x2 . f16x2 (one v_dot2_f32_f16 when available)
#if __has_builtin(__builtin_amdgcn_fdot2)
__device__ __forceinline__ float dot2f(u32 a, u32 b, float c) {
    return __builtin_amdgcn_fdot2(ash2(a), ash2(b), c, false);
}
#else
__device__ __forceinline__ float dot2f(u32 a, u32 b, float c) {
    half2_t ha = ash2(a), hb = ash2(b);
    c = fmaf((float)ha.x, (float)hb.x, c);
    c = fmaf((float)ha.y, (float)hb.y, c);
    return c;
}
#endif

// broadcast lane l's f32 to all lanes via v_readlane (VALU pipe, NOT LDS --
// the per-CU LDS pipe is the epilogue's contended resource; VALU is 4x/CU)
__device__ __forceinline__ float rl32(float v, int l) {
    return __uint_as_float(__builtin_amdgcn_readlane(__float_as_uint(v), l));
}

// async global->LDS: each active lane moves 16 B; LDS dest = base + lane*16
__device__ __forceinline__ void gload_lds16(const void* g, void* l) {
    __builtin_amdgcn_global_load_lds(
        (const __attribute__((address_space(1))) void*)g,
        (__attribute__((address_space(3))) void*)l, 16, 0, 0);
}

// ---------- prep kernel: repack (blocks < ablocks) + fill (rest) -------------
// Two independent workloads in ONE dispatch so they overlap on CUs.
// cnt is zeroed beforehand by hipMemsetAsync (stream-ordered).
__global__ __launch_bounds__(256) void prep_kernel(
    const float* __restrict__ x0,
    const float* __restrict__ x1,
    const float* __restrict__ x2,
    uint4* __restrict__ xph4,
    const float* __restrict__ rij,
    const int*   __restrict__ idx_i,
    const int*   __restrict__ idx_j,
    int*    __restrict__ cnt,
    float4* __restrict__ recs,
    int N, int E, int ablocks)
{
    if ((int)blockIdx.x < ablocks) {
        // ---- repack x -> xph[N][C][8] u32 bf16-pairs ----
        int t = blockIdx.x * 256 + threadIdx.x;
        if (t >= N * CH) return;

        float f[13];
        f[0] = x0[t];
        const float* p1 = x1 + (size_t)t * 3;
#pragma unroll
        for (int a = 0; a < 3; a++) f[1 + a] = p1[a];
        const float* p2 = x2 + (size_t)t * 9;
#pragma unroll
        for (int q = 0; q < 9; q++) f[4 + q] = p2[q];

        u32 d[8];
#pragma unroll
        for (int qp = 0; qp < 6; qp++)
            d[qp] = bf16r(f[2 * qp]) | (bf16r(f[2 * qp + 1]) << 16);
        d[6] = bf16r(f[12]);    // hi halfword = 0 pad
        d[7] = 0u;
        uint4* xo = xph4 + (size_t)t * 2;
        xo[0] = make_uint4(d[0], d[1], d[2], d[3]);
        xo[1] = make_uint4(d[4], d[5], d[6], d[7]);
    } else {
        // ---- per-edge geometry+RBF -> 32 B record in node slot ----
        int e = ((int)blockIdx.x - ablocks) * 256 + threadIdx.x;
        if (e >= E) return;

        float rx = rij[e * 3 + 0], ry = rij[e * 3 + 1], rz = rij[e * 3 + 2];
        float dn = sqrtf(rx * rx + ry * ry + rz * rz);
        float d = fmaxf(dn, 1e-6f);
        float inv = 1.0f / d;

        float rbf[NBASIS];
#pragma unroll
        for (int k = 0; k < NBASIS; k++) {
            float ck = 5.0f * (float)k / (float)(NBASIS - 1);
            float del = d - ck;
            rbf[k] = __expf(-4.0f * del * del);
        }
        float dc = fminf(d, 5.0f);
        float fc = 0.5f * (__cosf((float)M_PI * dc * 0.2f) + 1.0f);
        float scale = fc * 0.1f;   // cutoff * 1/NORM_FACTOR folded in

        int i = idx_i[e];
        int pos = atomicAdd(&cnt[i], 1);
        if (pos >= MAXDEG) return;

        u32 w3  = ((u32)idx_j[e] << 16) | bf16r(scale);
        u32 p01 = f16pk(rbf[0] * scale, rbf[1] * scale);
        u32 p23 = f16pk(rbf[2] * scale, rbf[3] * scale);
        u32 p45 = f16pk(rbf[4] * scale, rbf[5] * scale);
        u32 p67 = f16pk(rbf[6] * scale, rbf[7] * scale);

        float4* r = recs + 2 * (size_t)(i * MAXDEG + pos);
        r[0] = make_float4(rx * inv, ry * inv, rz * inv, __uint_as_float(w3));
        r[1] = make_float4(__uint_as_float(p01), __uint_as_float(p23),
                           __uint_as_float(p45), __uint_as_float(p67));
    }
}

// ---------- edge + node kernel ----------------------------------------------
// R10 edge loop byte-identical. R14: the node epilogue is WAVE-LOCAL and
// BARRIER-FREE -- after the shfl_xor combine every lane holds the full
// A0/A1/A2 in registers, so channel broadcasts use v_readlane (VALU pipe,
// 4x/CU) instead of LDS broadcasts (serial per-CU pipe: ~400 reads/node was
// the R12/R13 epilogue's ~35us). No sA/sy0 staging, no post-loop barriers ->
// waves exit independently (R10 block-turnover restored). Weights read from
// global (L1-hot, coalesced). Math bit-identical (same FMA order).
// Launch-bounds lesson (R2/R3): 2nd arg w caps VGPR at ~256/w; (256,1) is
// the proven no-spill setting (tripwire: WRITE_SIZE >> 33 MB).
__global__ __launch_bounds__(256, 1) void edge_node_kernel(
    const float4*   __restrict__ recs,
    const uint4*    __restrict__ xph4,    // [N][C][8 dwords] bf16-pairs
    const int*      __restrict__ cnt,     // [N]
    const float*    __restrict__ W_rbf,   // [NBASIS][NPATH*C]
    const float*    __restrict__ b_rbf,   // [NPATH*C]
    const float* __restrict__ x0,         // [N][C]       residual
    const float* __restrict__ x1,         // [N][C][3]
    const float* __restrict__ x2,         // [N][C][9]
    const float* __restrict__ Wmix0, const float* __restrict__ Wmix1,
    const float* __restrict__ Wmix2,
    const float* __restrict__ coupling,
    const float* __restrict__ Wg0, const float* __restrict__ Wg1,
    const float* __restrict__ Wg2,
    const float* __restrict__ bg0, const float* __restrict__ bg1,
    const float* __restrict__ bg2,
    float* __restrict__ out, int N)
{
    __shared__ __align__(16) char smem[SMEM_TOTAL];
    uint4*  sW4  = (uint4*)smem;
    float4* srec = (float4*)(smem + SM_SREC_OFF);

    int tid  = threadIdx.x;
    int wid  = tid >> 6;
    int lane = tid & 63;
    int half = lane >> 5;
    int c    = lane & 31;
    int n    = blockIdx.x * NW + wid;
    bool valid = (n < N);
    int nn = valid ? n : (N - 1);     // safe addressing for inactive waves

    // ---- 1. per-wave async staging of this node's 40 records (in flight) ----
    const char* gbase = (const char*)(recs + 2 * (size_t)nn * MAXDEG);
    {
        char* lbase = (char*)(srec + (size_t)wid * (MAXDEG * 2));
        gload_lds16(gbase + lane * 16, lbase);                    // slots 0..31
        if (lane < 16)
            gload_lds16(gbase + 1024 + lane * 16, lbase + 1024);  // slots 32..39
    }

    // ---- 2. prologue j's straight from global (overlaps staging latency) ----
    const u32* recw = (const u32*)gbase;
    u32 w30 = recw[half * 8 + 3];
    u32 w31 = recw[(half + 2) * 8 + 3];
    u32 w32 = recw[(half + 4) * 8 + 3];
    int deg_g = cnt[nn];              // scalar load, overlaps everything below

    // ---- 3. cooperative weight load -> LDS as f16-pair uint4 planes ---------
#pragma unroll
    for (int i = 0; i < 2; i++) {
        int idx = tid + i * 256;
        if (idx < NPATH * CH) {
            int cc = idx & 31, p = idx >> 5;
            const float* w = W_rbf + p * CH + cc;   // stride NPATH*CH per k
            uint4 v;
            v.x = f16pk(w[0 * NPATH * CH], w[1 * NPATH * CH]);
            v.y = f16pk(w[2 * NPATH * CH], w[3 * NPATH * CH]);
            v.z = f16pk(w[4 * NPATH * CH], w[5 * NPATH * CH]);
            v.w = f16pk(w[6 * NPATH * CH], w[7 * NPATH * CH]);
            sW4[idx] = v;
        }
    }

    // bias: 11 loop-invariant regs straight from global (small, L1-resident)
    float breg[NPATH];
#pragma unroll
    for (int p = 0; p < NPATH; p++) breg[p] = b_rbf[p * CH + c];

    auto gath = [&](uint4& ga, uint4& gb, u32 w3) {
        int j = (int)(w3 >> 16);
        j = j < N ? j : N - 1;                      // clamp garbage slots
        const uint4* g = xph4 + (((size_t)j * CH + c) << 1);
        ga = g[0];
        gb = g[1];
    };

    uint4 G0a, G0b, G1a, G1b, G2a, G2b;
    gath(G0a, G0b, w30);
    gath(G1a, G1b, w31);
    gath(G2a, G2b, w32);

    __syncthreads();     // drains staging + prologue; sW4/srec visible

    int deg = valid ? (deg_g < MAXDEG ? deg_g : MAXDEG) : 0;

    int s0 = half, s1 = half + 2, s2 = half + 4;
    bool v0 = s0 < deg, v1 = s1 < deg, v2 = s2 < deg;

    float A0 = 0.0f, A1[3] = {0, 0, 0}, A2[9] = {0, 0, 0, 0, 0, 0, 0, 0, 0};

    const uint4* sW4c = sW4 + c;    // single LDS base; paths via imm offsets

    auto compute = [&](float4 ra, float4 rb4, uint4 ga, uint4 gb) {
        float G[13];
        G[0]  = bf16lo(ga.x); G[1]  = bf16hi(ga.x);
        G[2]  = bf16lo(ga.y); G[3]  = bf16hi(ga.y);
        G[4]  = bf16lo(ga.z); G[5]  = bf16hi(ga.z);
        G[6]  = bf16lo(ga.w); G[7]  = bf16hi(ga.w);
        G[8]  = bf16lo(gb.x); G[9]  = bf16hi(gb.x);
        G[10] = bf16lo(gb.y); G[11] = bf16hi(gb.y);
        G[12] = bf16lo(gb.z);

        float scale = bf16lo(__float_as_uint(ra.w));
        u32 pb0 = __float_as_uint(rb4.x), pb1 = __float_as_uint(rb4.y),
            pb2 = __float_as_uint(rb4.z), pb3 = __float_as_uint(rb4.w);

        float fv[NPATH];
#pragma unroll
        for (int p = 0; p < NPATH; p++) {
            uint4 wp = sW4c[p * CH];            // ds_read_b128: whole path row
            float acc = scale * breg[p];
            acc = dot2f(pb0, wp.x, acc);
            acc = dot2f(pb1, wp.y, acc);
            acc = dot2f(pb2, wp.z, acc);
            acc = dot2f(pb3, wp.w, acc);
            fv[p] = acc;
        }

        float hv[3] = {ra.x, ra.y, ra.z};
        float xj0 = G[0];
        float xv[3] = {G[1], G[2], G[3]};
        float x1r = xv[0] * hv[0] + xv[1] * hv[1] + xv[2] * hv[2];
        float x2r[3];
#pragma unroll
        for (int a = 0; a < 3; a++)
            x2r[a] = G[4 + a * 3 + 0] * hv[0] + G[4 + a * 3 + 1] * hv[1]
                   + G[4 + a * 3 + 2] * hv[2];
        float x2rr = x2r[0] * hv[0] + x2r[1] * hv[1] + x2r[2] * hv[2];

        A0 += fv[0] * xj0 + fv[5] * x1r + fv[10] * x2rr;

        float s01 = fv[1] * xj0 + fv[6] * x1r;
#pragma unroll
        for (int a = 0; a < 3; a++)
            A1[a] += s01 * hv[a] + fv[3] * xv[a] + fv[8] * x2r[a];

        float f2x = fv[2] * xj0;
#pragma unroll
        for (int a = 0; a < 3; a++) {
            float w = f2x * hv[a] + fv[4] * xv[a] + fv[9] * x2r[a];
#pragma unroll
            for (int b = 0; b < 3; b++)
                A2[a * 3 + b] += w * hv[b] + fv[7] * G[4 + a * 3 + b];
        }
    };

    const float4* sr = srec + (size_t)wid * (MAXDEG * 2);

    // ---- 4. 3-stage pipelined edge loop (gathers prefetched 2 phases) -------
    while (v0) {
        bool n0 = (s0 + 6 < deg);
        bool n1 = v1 && (s1 + 6 < deg);
        bool n2 = v2 && (s2 + 6 < deg);

        float4 ra0 = sr[2 * s0], rb0 = sr[2 * s0 + 1];
        int t0 = s0 + 6 < MAXDEG ? s0 + 6 : MAXDEG - 1;
        u32 w0n = __float_as_uint(sr[2 * t0].w);
        float4 ra1, rb1, ra2, rb2;
        u32 w1n = 0, w2n = 0;
        if (v1) {
            ra1 = sr[2 * s1]; rb1 = sr[2 * s1 + 1];
            int t1 = s1 + 6 < MAXDEG ? s1 + 6 : MAXDEG - 1;
            w1n = __float_as_uint(sr[2 * t1].w);
        }
        if (v2) {
            ra2 = sr[2 * s2]; rb2 = sr[2 * s2 + 1];
            int t2 = s2 + 6 < MAXDEG ? s2 + 6 : MAXDEG - 1;
            w2n = __float_as_uint(sr[2 * t2].w);
        }

        compute(ra0, rb0, G0a, G0b);
        if (n0) gath(G0a, G0b, w0n);
        s0 += 6; v0 = n0;

        if (v1) {
            compute(ra1, rb1, G1a, G1b);
            if (n1) gath(G1a, G1b, w1n);
            s1 += 6; v1 = n1;
        }
        if (v2) {
            compute(ra2, rb2, G2a, G2b);
            if (n2) gath(G2a, G2b, w2n);
            s2 += 6; v2 = n2;
        }
    }

    // combine halves -> ALL 64 lanes hold the node's full A0/A1/A2 sums
    A0 += __shfl_xor(A0, 32);
#pragma unroll
    for (int a = 0; a < 3; a++) A1[a] += __shfl_xor(A1[a], 32);
#pragma unroll
    for (int q = 0; q < 9; q++) A2[q] += __shfl_xor(A2[q], 32);

    if (!valid) return;   // no barriers below -- safe wave-local exit

    // ---- 5. wave-local node epilogue (register broadcasts via readlane) ----
    int d = c;

    // y0 on all lanes (gates need all channels of y0)
    float y0 = 0.0f;
#pragma unroll 8
    for (int cc = 0; cc < CH; cc++)
        y0 = fmaf(rl32(A0, cc), Wmix0[cc * CH + d], y0);
    {
        float cp0 = coupling[0 * CH + d], cp3 = coupling[3 * CH + d],
              cp6 = coupling[6 * CH + d];
        float n1v = A1[0] * A1[0] + A1[1] * A1[1] + A1[2] * A1[2];
        float n2v = 0.0f;
#pragma unroll
        for (int q = 0; q < 9; q++) n2v = fmaf(A2[q], A2[q], n2v);
        y0 += cp0 * A0 * A0 + cp3 * n1v + cp6 * n2v;
    }

    float* o = out + (size_t)n * NPF + d * NF;   // [N][C][13] feature-minor

    if (half == 0) {
        float y1[3] = {0, 0, 0};
#pragma unroll 4
        for (int cc = 0; cc < CH; cc++) {
            float w1 = Wmix1[cc * CH + d];
            y1[0] = fmaf(rl32(A1[0], cc), w1, y1[0]);
            y1[1] = fmaf(rl32(A1[1], cc), w1, y1[1]);
            y1[2] = fmaf(rl32(A1[2], cc), w1, y1[2]);
        }
        float cp1 = coupling[1 * CH + d], cp5 = coupling[5 * CH + d];
#pragma unroll
        for (int a = 0; a < 3; a++) {
            float a2a1 = A2[a * 3 + 0] * A1[0] + A2[a * 3 + 1] * A1[1]
                       + A2[a * 3 + 2] * A1[2];
            y1[a] += cp1 * A0 * A1[a] + cp5 * a2a1;
        }

        float g0 = bg0[d], g1 = bg1[d];
#pragma unroll 8
        for (int cc = 0; cc < CH; cc++) {
            float yv = rl32(y0, cc);
            g0 = fmaf(yv, Wg0[cc * CH + d], g0);
            g1 = fmaf(yv, Wg1[cc * CH + d], g1);
        }
        g0 = silu_f(g0);
        g1 = silu_f(g1);

        const float* xs0 = x0 + (size_t)n * CH;
        const float* xs1 = x1 + ((size_t)n * CH + d) * 3;
        o[0] = xs0[d] + g0;
#pragma unroll
        for (int a = 0; a < 3; a++)
            o[1 + a] = xs1[a] + y1[a] * g1;
    } else {
        float y2[9] = {0, 0, 0, 0, 0, 0, 0, 0, 0};
#pragma unroll 4
        for (int cc = 0; cc < CH; cc++) {
            float w2 = Wmix2[cc * CH + d];
#pragma unroll
            for (int q = 0; q < 9; q++)
                y2[q] = fmaf(rl32(A2[q], cc), w2, y2[q]);
        }
        float cp2 = coupling[2 * CH + d], cp4 = coupling[4 * CH + d],
              cp7 = coupling[7 * CH + d];
#pragma unroll
        for (int a = 0; a < 3; a++) {
#pragma unroll
            for (int b = 0; b < 3; b++) {
                float a2a2 = A2[a * 3 + 0] * A2[0 * 3 + b]
                           + A2[a * 3 + 1] * A2[1 * 3 + b]
                           + A2[a * 3 + 2] * A2[2 * 3 + b];
                y2[a * 3 + b] += cp2 * A0 * A2[a * 3 + b]
                               + cp4 * A1[a] * A1[b] + cp7 * a2a2;
            }
        }

        float g2 = bg2[d];
#pragma unroll 8
        for (int cc = 0; cc < CH; cc++)
            g2 = fmaf(rl32(y0, cc), Wg2[cc * CH + d], g2);
        g2 = silu_f(g2);

        const float* xs2 = x2 + ((size_t)n * CH + d) * 9;
#pragma unroll
        for (int q = 0; q < 9; q++)
            o[4 + q] = xs2[q] + y2[q] * g2;
    }
}

extern "C" void kernel_launch(void* const* d_in, const int* in_sizes, int n_in,
                              void* d_out, int out_size, void* d_ws, size_t ws_size,
                              hipStream_t stream) {
    const float* rij      = (const float*)d_in[0];
    const float* x0       = (const float*)d_in[1];
    const float* x1       = (const float*)d_in[2];
    const float* x2       = (const float*)d_in[3];
    const int*   idx_i    = (const int*)d_in[4];
    const int*   idx_j    = (const int*)d_in[5];
    const float* W_rbf    = (const float*)d_in[6];
    const float* b_rbf    = (const float*)d_in[7];
    const float* Wmix0    = (const float*)d_in[8];
    const float* Wmix1    = (const float*)d_in[9];
    const float* Wmix2    = (const float*)d_in[10];
    const float* coupling = (const float*)d_in[11];
    const float* Wg0      = (const float*)d_in[12];
    const float* Wg1      = (const float*)d_in[13];
    const float* Wg2      = (const float*)d_in[14];
    const float* bg0      = (const float*)d_in[15];
    const float* bg1      = (const float*)d_in[16];
    const float* bg2      = (const float*)d_in[17];

    int E = in_sizes[4];
    int N = in_sizes[1] / CH;

    // ws: recs[N*MAXDEG*32B] | xph[N*C*8 u32] | cnt[N]
    float4* recs = (float4*)d_ws;
    uint4*  xph4 = (uint4*)(recs + 2 * (size_t)N * MAXDEG);
    int*    cnt  = (int*)(xph4 + (size_t)N * CH * 2);

    hipMemsetAsync(cnt, 0, (size_t)N * sizeof(int), stream);

    int ablocks = (N * CH + 255) / 256;
    int fblocks = (E + 255) / 256;
    prep_kernel<<<ablocks + fblocks, 256, 0, stream>>>(
        x0, x1, x2, xph4, rij, idx_i, idx_j, cnt, recs, N, E, ablocks);

    edge_node_kernel<<<(N + NW - 1) / NW, 256, 0, stream>>>(
        recs, xph4, cnt, W_rbf, b_rbf, x0, x1, x2,
        Wmix0, Wmix1, Wmix2, coupling, Wg0, Wg1, Wg2, bg0, bg1, bg2,
        (float*)d_out, N);
}

// Round 15
// 212.620 us; speedup vs baseline: 1.3020x; 1.3020x over previous
//
#include <hip/hip_runtime.h>
#include <cmath>

#define CH 32
#define NBASIS 8
#define NPATH 11
#define NF 13            // features per channel: 1 + 3 + 9
#define NPF (NF * CH)    // 416 f32 per node
#define MAXDEG 40        // slot capacity; Poisson(10) -> P(overflow) ~ 1e-8
#define NW 4             // nodes (waves) per 256-thread block (edge kernel)

typedef unsigned int u32;
typedef __fp16 half2_t __attribute__((ext_vector_type(2)));

// ---- LDS union (edge regions die before node epilogue begins) --------------
// [0, 5632)          sW4   edge f16-pair weight planes
// [5632, 10752)      srec  edge records
// [0, 24576)         sW6   node 6x(32x32) f32 weights (overwrites edge regions)
// [24576, 31232)     sA    4 x NPF A-sums
// [31232, 31744)     sy0   4 x CH
#define SM_SREC_OFF 5632
#define SM_SA_OFF   24576
#define SM_SY0_OFF  31232
#define SMEM_TOTAL  31744

__device__ __forceinline__ float silu_f(float x) {
    return x / (1.0f + __expf(-x));
}

__device__ __forceinline__ u32 bf16r(float x) {   // round-to-nearest bf16 bits
    return (__float_as_uint(x) + 0x8000u) >> 16;
}
__device__ __forceinline__ float bf16lo(u32 w) {  // low 16 bits -> f32
    return __uint_as_float(w << 16);
}
__device__ __forceinline__ float bf16hi(u32 w) {  // high 16 bits -> f32
    return __uint_as_float(w & 0xffff0000u);
}

// pack two f32 -> f16x2 dword (v_cvt_pkrtz_f16_f32)
__device__ __forceinline__ u32 f16pk(float a, float b) {
    union { half2_t h; u32 u; } cv;
    cv.h = __builtin_amdgcn_cvt_pkrtz(a, b);
    return cv.u;
}
__device__ __forceinline__ half2_t ash2(u32 w) {
    union { u32 u; half2_t h; } cv; cv.u = w; return cv.h;
}

// f32 += f16x2 . f16x2 (one v_dot2_f32_f16 when available)
#if __has_builtin(__builtin_amdgcn_fdot2)
__device__ __forceinline__ float dot2f(u32 a, u32 b, float c) {
    return __builtin_amdgcn_fdot2(ash2(a), ash2(b), c, false);
}
#else
__device__ __forceinline__ float dot2f(u32 a, u32 b, float c) {
    half2_t ha = ash2(a), hb = ash2(b);
    c = fmaf((float)ha.x, (float)hb.x, c);
    c = fmaf((float)ha.y, (float)hb.y, c);
    return c;
}
#endif

// async global->LDS: each active lane moves 16 B; LDS dest = base + lane*16
__device__ __forceinline__ void gload_lds16(const void* g, void* l) {
    __builtin_amdgcn_global_load_lds(
        (const __attribute__((address_space(1))) void*)g,
        (__attribute__((address_space(3))) void*)l, 16, 0, 0);
}

// ---------- prep kernel: repack (blocks < ablocks) + fill (rest) -------------
// Two independent workloads in ONE dispatch so they overlap on CUs.
// cnt is zeroed beforehand by hipMemsetAsync (stream-ordered).
__global__ __launch_bounds__(256) void prep_kernel(
    const float* __restrict__ x0,
    const float* __restrict__ x1,
    const float* __restrict__ x2,
    uint4* __restrict__ xph4,
    const float* __restrict__ rij,
    const int*   __restrict__ idx_i,
    const int*   __restrict__ idx_j,
    int*    __restrict__ cnt,
    float4* __restrict__ recs,
    int N, int E, int ablocks)
{
    if ((int)blockIdx.x < ablocks) {
        // ---- repack x -> xph[N][C][8] u32 bf16-pairs ----
        int t = blockIdx.x * 256 + threadIdx.x;
        if (t >= N * CH) return;

        float f[13];
        f[0] = x0[t];
        const float* p1 = x1 + (size_t)t * 3;
#pragma unroll
        for (int a = 0; a < 3; a++) f[1 + a] = p1[a];
        const float* p2 = x2 + (size_t)t * 9;
#pragma unroll
        for (int q = 0; q < 9; q++) f[4 + q] = p2[q];

        u32 d[8];
#pragma unroll
        for (int qp = 0; qp < 6; qp++)
            d[qp] = bf16r(f[2 * qp]) | (bf16r(f[2 * qp + 1]) << 16);
        d[6] = bf16r(f[12]);    // hi halfword = 0 pad
        d[7] = 0u;
        uint4* xo = xph4 + (size_t)t * 2;
        xo[0] = make_uint4(d[0], d[1], d[2], d[3]);
        xo[1] = make_uint4(d[4], d[5], d[6], d[7]);
    } else {
        // ---- per-edge geometry+RBF -> 32 B record in node slot ----
        int e = ((int)blockIdx.x - ablocks) * 256 + threadIdx.x;
        if (e >= E) return;

        float rx = rij[e * 3 + 0], ry = rij[e * 3 + 1], rz = rij[e * 3 + 2];
        float dn = sqrtf(rx * rx + ry * ry + rz * rz);
        float d = fmaxf(dn, 1e-6f);
        float inv = 1.0f / d;

        float rbf[NBASIS];
#pragma unroll
        for (int k = 0; k < NBASIS; k++) {
            float ck = 5.0f * (float)k / (float)(NBASIS - 1);
            float del = d - ck;
            rbf[k] = __expf(-4.0f * del * del);
        }
        float dc = fminf(d, 5.0f);
        float fc = 0.5f * (__cosf((float)M_PI * dc * 0.2f) + 1.0f);
        float scale = fc * 0.1f;   // cutoff * 1/NORM_FACTOR folded in

        int i = idx_i[e];
        int pos = atomicAdd(&cnt[i], 1);
        if (pos >= MAXDEG) return;

        u32 w3  = ((u32)idx_j[e] << 16) | bf16r(scale);
        u32 p01 = f16pk(rbf[0] * scale, rbf[1] * scale);
        u32 p23 = f16pk(rbf[2] * scale, rbf[3] * scale);
        u32 p45 = f16pk(rbf[4] * scale, rbf[5] * scale);
        u32 p67 = f16pk(rbf[6] * scale, rbf[7] * scale);

        float4* r = recs + 2 * (size_t)(i * MAXDEG + pos);
        r[0] = make_float4(rx * inv, ry * inv, rz * inv, __uint_as_float(w3));
        r[1] = make_float4(__uint_as_float(p01), __uint_as_float(p23),
                           __uint_as_float(p45), __uint_as_float(p67));
    }
}

// ---------- edge + node kernel (R12 configuration -- best measured) ----------
// R10 edge loop byte-identical; node self-interaction runs as an IN-BLOCK
// epilogue (A-sums to LDS, six 32x32 weights staged to LDS union, wave-uniform
// half-split). Epilogue-pipe ledger across rounds: LDS-staged 94.5us (R12) <
// global-weight 97.7 (R13) < readlane 153 (R14) -- this is the optimum.
// Launch-bounds lesson (R2/R3): 2nd arg w caps VGPR at ~256/w; (256,1) is
// the proven no-spill setting (tripwire: WRITE_SIZE >> 33 MB).
__global__ __launch_bounds__(256, 1) void edge_node_kernel(
    const float4*   __restrict__ recs,
    const uint4*    __restrict__ xph4,    // [N][C][8 dwords] bf16-pairs
    const int*      __restrict__ cnt,     // [N]
    const float*    __restrict__ W_rbf,   // [NBASIS][NPATH*C]
    const float*    __restrict__ b_rbf,   // [NPATH*C]
    const float* __restrict__ x0,         // [N][C]       residual
    const float* __restrict__ x1,         // [N][C][3]
    const float* __restrict__ x2,         // [N][C][9]
    const float* __restrict__ Wmix0, const float* __restrict__ Wmix1,
    const float* __restrict__ Wmix2,
    const float* __restrict__ coupling,
    const float* __restrict__ Wg0, const float* __restrict__ Wg1,
    const float* __restrict__ Wg2,
    const float* __restrict__ bg0, const float* __restrict__ bg1,
    const float* __restrict__ bg2,
    float* __restrict__ out, int N)
{
    __shared__ __align__(16) char smem[SMEM_TOTAL];
    uint4*  sW4  = (uint4*)smem;                      // edge
    float4* srec = (float4*)(smem + SM_SREC_OFF);     // edge
    float*  sW6  = (float*)smem;                      // node (after barrier)
    float*  sA   = (float*)(smem + SM_SA_OFF);        // [4][NPF]
    float*  sy0  = (float*)(smem + SM_SY0_OFF);       // [4][CH]

    int tid  = threadIdx.x;
    int wid  = tid >> 6;
    int lane = tid & 63;
    int half = lane >> 5;
    int c    = lane & 31;
    int n    = blockIdx.x * NW + wid;
    bool valid = (n < N);
    int nn = valid ? n : (N - 1);     // safe addressing for inactive waves

    // ---- 1. per-wave async staging of this node's 40 records (in flight) ----
    const char* gbase = (const char*)(recs + 2 * (size_t)nn * MAXDEG);
    {
        char* lbase = (char*)(srec + (size_t)wid * (MAXDEG * 2));
        gload_lds16(gbase + lane * 16, lbase);                    // slots 0..31
        if (lane < 16)
            gload_lds16(gbase + 1024 + lane * 16, lbase + 1024);  // slots 32..39
    }

    // ---- 2. prologue j's straight from global (overlaps staging latency) ----
    const u32* recw = (const u32*)gbase;
    u32 w30 = recw[half * 8 + 3];
    u32 w31 = recw[(half + 2) * 8 + 3];
    u32 w32 = recw[(half + 4) * 8 + 3];
    int deg_g = cnt[nn];              // scalar load, overlaps everything below

    // ---- 3. cooperative weight load -> LDS as f16-pair uint4 planes ---------
#pragma unroll
    for (int i = 0; i < 2; i++) {
        int idx = tid + i * 256;
        if (idx < NPATH * CH) {
            int cc = idx & 31, p = idx >> 5;
            const float* w = W_rbf + p * CH + cc;   // stride NPATH*CH per k
            uint4 v;
            v.x = f16pk(w[0 * NPATH * CH], w[1 * NPATH * CH]);
            v.y = f16pk(w[2 * NPATH * CH], w[3 * NPATH * CH]);
            v.z = f16pk(w[4 * NPATH * CH], w[5 * NPATH * CH]);
            v.w = f16pk(w[6 * NPATH * CH], w[7 * NPATH * CH]);
            sW4[idx] = v;
        }
    }

    // bias: 11 loop-invariant regs straight from global (small, L1-resident)
    float breg[NPATH];
#pragma unroll
    for (int p = 0; p < NPATH; p++) breg[p] = b_rbf[p * CH + c];

    auto gath = [&](uint4& ga, uint4& gb, u32 w3) {
        int j = (int)(w3 >> 16);
        j = j < N ? j : N - 1;                      // clamp garbage slots
        const uint4* g = xph4 + (((size_t)j * CH + c) << 1);
        ga = g[0];
        gb = g[1];
    };

    uint4 G0a, G0b, G1a, G1b, G2a, G2b;
    gath(G0a, G0b, w30);
    gath(G1a, G1b, w31);
    gath(G2a, G2b, w32);

    __syncthreads();     // drains staging + prologue; sW4/srec visible

    int deg = valid ? (deg_g < MAXDEG ? deg_g : MAXDEG) : 0;

    int s0 = half, s1 = half + 2, s2 = half + 4;
    bool v0 = s0 < deg, v1 = s1 < deg, v2 = s2 < deg;

    float A0 = 0.0f, A1[3] = {0, 0, 0}, A2[9] = {0, 0, 0, 0, 0, 0, 0, 0, 0};

    const uint4* sW4c = sW4 + c;    // single LDS base; paths via imm offsets

    auto compute = [&](float4 ra, float4 rb4, uint4 ga, uint4 gb) {
        float G[13];
        G[0]  = bf16lo(ga.x); G[1]  = bf16hi(ga.x);
        G[2]  = bf16lo(ga.y); G[3]  = bf16hi(ga.y);
        G[4]  = bf16lo(ga.z); G[5]  = bf16hi(ga.z);
        G[6]  = bf16lo(ga.w); G[7]  = bf16hi(ga.w);
        G[8]  = bf16lo(gb.x); G[9]  = bf16hi(gb.x);
        G[10] = bf16lo(gb.y); G[11] = bf16hi(gb.y);
        G[12] = bf16lo(gb.z);

        float scale = bf16lo(__float_as_uint(ra.w));
        u32 pb0 = __float_as_uint(rb4.x), pb1 = __float_as_uint(rb4.y),
            pb2 = __float_as_uint(rb4.z), pb3 = __float_as_uint(rb4.w);

        float fv[NPATH];
#pragma unroll
        for (int p = 0; p < NPATH; p++) {
            uint4 wp = sW4c[p * CH];            // ds_read_b128: whole path row
            float acc = scale * breg[p];
            acc = dot2f(pb0, wp.x, acc);
            acc = dot2f(pb1, wp.y, acc);
            acc = dot2f(pb2, wp.z, acc);
            acc = dot2f(pb3, wp.w, acc);
            fv[p] = acc;
        }

        float hv[3] = {ra.x, ra.y, ra.z};
        float xj0 = G[0];
        float xv[3] = {G[1], G[2], G[3]};
        float x1r = xv[0] * hv[0] + xv[1] * hv[1] + xv[2] * hv[2];
        float x2r[3];
#pragma unroll
        for (int a = 0; a < 3; a++)
            x2r[a] = G[4 + a * 3 + 0] * hv[0] + G[4 + a * 3 + 1] * hv[1]
                   + G[4 + a * 3 + 2] * hv[2];
        float x2rr = x2r[0] * hv[0] + x2r[1] * hv[1] + x2r[2] * hv[2];

        A0 += fv[0] * xj0 + fv[5] * x1r + fv[10] * x2rr;

        float s01 = fv[1] * xj0 + fv[6] * x1r;
#pragma unroll
        for (int a = 0; a < 3; a++)
            A1[a] += s01 * hv[a] + fv[3] * xv[a] + fv[8] * x2r[a];

        float f2x = fv[2] * xj0;
#pragma unroll
        for (int a = 0; a < 3; a++) {
            float w = f2x * hv[a] + fv[4] * xv[a] + fv[9] * x2r[a];
#pragma unroll
            for (int b = 0; b < 3; b++)
                A2[a * 3 + b] += w * hv[b] + fv[7] * G[4 + a * 3 + b];
        }
    };

    const float4* sr = srec + (size_t)wid * (MAXDEG * 2);

    // ---- 4. 3-stage pipelined edge loop (gathers prefetched 2 phases) -------
    while (v0) {
        bool n0 = (s0 + 6 < deg);
        bool n1 = v1 && (s1 + 6 < deg);
        bool n2 = v2 && (s2 + 6 < deg);

        float4 ra0 = sr[2 * s0], rb0 = sr[2 * s0 + 1];
        int t0 = s0 + 6 < MAXDEG ? s0 + 6 : MAXDEG - 1;
        u32 w0n = __float_as_uint(sr[2 * t0].w);
        float4 ra1, rb1, ra2, rb2;
        u32 w1n = 0, w2n = 0;
        if (v1) {
            ra1 = sr[2 * s1]; rb1 = sr[2 * s1 + 1];
            int t1 = s1 + 6 < MAXDEG ? s1 + 6 : MAXDEG - 1;
            w1n = __float_as_uint(sr[2 * t1].w);
        }
        if (v2) {
            ra2 = sr[2 * s2]; rb2 = sr[2 * s2 + 1];
            int t2 = s2 + 6 < MAXDEG ? s2 + 6 : MAXDEG - 1;
            w2n = __float_as_uint(sr[2 * t2].w);
        }

        compute(ra0, rb0, G0a, G0b);
        if (n0) gath(G0a, G0b, w0n);
        s0 += 6; v0 = n0;

        if (v1) {
            compute(ra1, rb1, G1a, G1b);
            if (n1) gath(G1a, G1b, w1n);
            s1 += 6; v1 = n1;
        }
        if (v2) {
            compute(ra2, rb2, G2a, G2b);
            if (n2) gath(G2a, G2b, w2n);
            s2 += 6; v2 = n2;
        }
    }

    // combine halves -> all 64 lanes hold full sums; stage into sA (LDS)
    A0 += __shfl_xor(A0, 32);
#pragma unroll
    for (int a = 0; a < 3; a++) A1[a] += __shfl_xor(A1[a], 32);
#pragma unroll
    for (int q = 0; q < 9; q++) A2[q] += __shfl_xor(A2[q], 32);

    {
        float* an = sA + wid * NPF;       // wave-private region
        if (half == 0) {
            an[c] = A0;
#pragma unroll
            for (int a = 0; a < 3; a++) an[(1 + a) * CH + c] = A1[a];
        } else {
#pragma unroll
            for (int q = 0; q < 9; q++) an[(4 + q) * CH + c] = A2[q];
        }
    }
    __syncthreads();     // sA complete; edge LDS regions now dead

    // ---- 5. node epilogue: stage six 32x32 weights into the union ----------
#pragma unroll
    for (int r = 0; r < 4; r++) {
        int idx = r * 256 + tid;
        sW6[0 * 1024 + idx] = Wmix0[idx];
        sW6[1 * 1024 + idx] = Wmix1[idx];
        sW6[2 * 1024 + idx] = Wmix2[idx];
        sW6[3 * 1024 + idx] = Wg0[idx];
        sW6[4 * 1024 + idx] = Wg1[idx];
        sW6[5 * 1024 + idx] = Wg2[idx];
    }
    __syncthreads();

    int nl = (tid >> 5) & 3;             // node slot 0..3
    int d  = tid & 31;
    int ng = blockIdx.x * NW + nl;
    bool phA = (tid < 128);              // wave-uniform half split (waves 0-1)
    bool act = (ng < N);
    const float* An = sA + nl * NPF;

    float a0d = An[d];
    float a1d[3], a2d[9];
#pragma unroll
    for (int a = 0; a < 3; a++) a1d[a] = An[(1 + a) * CH + d];
#pragma unroll
    for (int q = 0; q < 9; q++) a2d[q] = An[(4 + q) * CH + d];

    float y2[9] = {0, 0, 0, 0, 0, 0, 0, 0, 0};
    if (phA) {
        // y0 (mix + couplings) -> sy0
        float y0 = 0.0f;
#pragma unroll 8
        for (int cc = 0; cc < CH; cc++)
            y0 = fmaf(An[cc], sW6[0 * 1024 + cc * CH + d], y0);
        float cp0 = coupling[0 * CH + d], cp3 = coupling[3 * CH + d],
              cp6 = coupling[6 * CH + d];
        float n1v = a1d[0] * a1d[0] + a1d[1] * a1d[1] + a1d[2] * a1d[2];
        float n2v = 0.0f;
#pragma unroll
        for (int q = 0; q < 9; q++) n2v = fmaf(a2d[q], a2d[q], n2v);
        y0 += cp0 * a0d * a0d + cp3 * n1v + cp6 * n2v;
        sy0[nl * CH + d] = y0;
    } else {
        // y2 channel mix runs in parallel with y0 (independent)
#pragma unroll 4
        for (int cc = 0; cc < CH; cc++) {
            float w2 = sW6[2 * 1024 + cc * CH + d];
#pragma unroll
            for (int q = 0; q < 9; q++)
                y2[q] = fmaf(An[(4 + q) * CH + cc], w2, y2[q]);
        }
    }
    __syncthreads();     // sy0 visible

    if (act && phA) {
        float y1[3] = {0, 0, 0};
#pragma unroll 4
        for (int cc = 0; cc < CH; cc++) {
            float w1 = sW6[1 * 1024 + cc * CH + d];
#pragma unroll
            for (int a = 0; a < 3; a++)
                y1[a] = fmaf(An[(1 + a) * CH + cc], w1, y1[a]);
        }
        float cp1 = coupling[1 * CH + d], cp5 = coupling[5 * CH + d];
#pragma unroll
        for (int a = 0; a < 3; a++) {
            float a2a1 = a2d[a * 3 + 0] * a1d[0] + a2d[a * 3 + 1] * a1d[1]
                       + a2d[a * 3 + 2] * a1d[2];
            y1[a] += cp1 * a0d * a1d[a] + cp5 * a2a1;
        }

        float g0 = bg0[d], g1 = bg1[d];
#pragma unroll 8
        for (int cc = 0; cc < CH; cc++) {
            float yv = sy0[nl * CH + cc];
            g0 = fmaf(yv, sW6[3 * 1024 + cc * CH + d], g0);
            g1 = fmaf(yv, sW6[4 * 1024 + cc * CH + d], g1);
        }
        g0 = silu_f(g0);
        g1 = silu_f(g1);

        const float* xs0 = x0 + (size_t)ng * CH;
        const float* xs1 = x1 + ((size_t)ng * CH + d) * 3;
        float* o = out + (size_t)ng * NPF + d * NF;
        o[0] = xs0[d] + g0;
#pragma unroll
        for (int a = 0; a < 3; a++)
            o[1 + a] = xs1[a] + y1[a] * g1;
    } else if (act) {
        float cp2 = coupling[2 * CH + d], cp4 = coupling[4 * CH + d],
              cp7 = coupling[7 * CH + d];
#pragma unroll
        for (int a = 0; a < 3; a++) {
#pragma unroll
            for (int b = 0; b < 3; b++) {
                float a2a2 = a2d[a * 3 + 0] * a2d[0 * 3 + b]
                           + a2d[a * 3 + 1] * a2d[1 * 3 + b]
                           + a2d[a * 3 + 2] * a2d[2 * 3 + b];
                y2[a * 3 + b] += cp2 * a0d * a2d[a * 3 + b]
                               + cp4 * a1d[a] * a1d[b] + cp7 * a2a2;
            }
        }

        float g2 = bg2[d];
#pragma unroll 8
        for (int cc = 0; cc < CH; cc++)
            g2 = fmaf(sy0[nl * CH + cc], sW6[5 * 1024 + cc * CH + d], g2);
        g2 = silu_f(g2);

        const float* xs2 = x2 + ((size_t)ng * CH + d) * 9;
        float* o = out + (size_t)ng * NPF + d * NF;
#pragma unroll
        for (int q = 0; q < 9; q++)
            o[4 + q] = xs2[q] + y2[q] * g2;
    }
}

extern "C" void kernel_launch(void* const* d_in, const int* in_sizes, int n_in,
                              void* d_out, int out_size, void* d_ws, size_t ws_size,
                              hipStream_t stream) {
    const float* rij      = (const float*)d_in[0];
    const float* x0       = (const float*)d_in[1];
    const float* x1       = (const float*)d_in[2];
    const float* x2       = (const float*)d_in[3];
    const int*   idx_i    = (const int*)d_in[4];
    const int*   idx_j    = (const int*)d_in[5];
    const float* W_rbf    = (const float*)d_in[6];
    const float* b_rbf    = (const float*)d_in[7];
    const float* Wmix0    = (const float*)d_in[8];
    const float* Wmix1    = (const float*)d_in[9];
    const float* Wmix2    = (const float*)d_in[10];
    const float* coupling = (const float*)d_in[11];
    const float* Wg0      = (const float*)d_in[12];
    const float* Wg1      = (const float*)d_in[13];
    const float* Wg2      = (const float*)d_in[14];
    const float* bg0      = (const float*)d_in[15];
    const float* bg1      = (const float*)d_in[16];
    const float* bg2      = (const float*)d_in[17];

    int E = in_sizes[4];
    int N = in_sizes[1] / CH;

    // ws: recs[N*MAXDEG*32B] | xph[N*C*8 u32] | cnt[N]
    float4* recs = (float4*)d_ws;
    uint4*  xph4 = (uint4*)(recs + 2 * (size_t)N * MAXDEG);
    int*    cnt  = (int*)(xph4 + (size_t)N * CH * 2);

    hipMemsetAsync(cnt, 0, (size_t)N * sizeof(int), stream);

    int ablocks = (N * CH + 255) / 256;
    int fblocks = (E + 255) / 256;
    prep_kernel<<<ablocks + fblocks, 256, 0, stream>>>(
        x0, x1, x2, xph4, rij, idx_i, idx_j, cnt, recs, N, E, ablocks);

    edge_node_kernel<<<(N + NW - 1) / NW, 256, 0, stream>>>(
        recs, xph4, cnt, W_rbf, b_rbf, x0, x1, x2,
        Wmix0, Wmix1, Wmix2, coupling, Wg0, Wg1, Wg2, bg0, bg1, bg2,
        (float*)d_out, N);
}